// Round 4
// baseline (8989.478 us; speedup 1.0000x reference)
//
#include <hip/hip_runtime.h>
#include <math.h>

#define KK 15
#define K1 16
#define NN 4096
#define BSZ 128
#define NT 512
#define RPT 8          // rows per thread in k_stage
#define NW 8           // waves per block
#define EPSI 0.1f
#define SMALLC 1e-20f
#define NITER 200
#define W2STRIDE 65536
#define OUT_A_ELEMS (BSZ * NN * KK)
#define TS 20          // wbufT row stride in floats

// ws layout (uint32 index):
// [0]=max_enc(0) [1]=neg(0) [2]=norm f32(0) [3]=arrive(0) [4]=done(0)
// [5]=min_enc(0xFFFFFFFF) [6]=filled f32 [7]=cinv f32
#define WS_VT0 16                    // 128 rows x 16 : warm-start vt
#define WS_TKO (WS_VT0 + BSZ * K1)   // 128 x 16 : top-k values (15 used)
#define WS_CLO (WS_TKO + BSZ * K1)   // 128 x 16 : Gamma0 col sums
#define WS_PSL (WS_CLO + BSZ * K1)   // 128 x 2 phase x 2 half x 16 : partials
#define WS_FLG (WS_PSL + BSZ * 64)   // 128 x 2 phase x 2 half : flags
#define WS_TOT (WS_FLG + BSZ * 4)    // total uints

// ---------- sortable float <-> uint encoding for atomic min/max ----------
__device__ __forceinline__ unsigned enc_f32(float f){
  unsigned u = __float_as_uint(f);
  return (u & 0x80000000u) ? ~u : (u | 0x80000000u);
}
__device__ __forceinline__ float dec_f32(unsigned e){
  unsigned u = (e & 0x80000000u) ? (e ^ 0x80000000u) : ~e;
  return __uint_as_float(u);
}

// ---------- 16-column lane-fold reduction ----------
__device__ __forceinline__ int fold_col(int lane){
  int l = lane & 15;
  return ((l & 1) << 3) | ((l & 2) << 1) | ((l & 4) >> 1) | ((l & 8) >> 3);
}

__device__ __forceinline__ float wave_fold16(const float p[K1], int lane){
  float a[8];
  {
    const bool hi = (lane & 1) != 0;
    #pragma unroll
    for (int j = 0; j < 8; ++j){
      float send = hi ? p[j] : p[j + 8];
      float keep = hi ? p[j + 8] : p[j];
      a[j] = keep + __shfl_xor(send, 1);
    }
  }
  float bq[4];
  {
    const bool hi = (lane & 2) != 0;
    #pragma unroll
    for (int j = 0; j < 4; ++j){
      float send = hi ? a[j] : a[j + 4];
      float keep = hi ? a[j + 4] : a[j];
      bq[j] = keep + __shfl_xor(send, 2);
    }
  }
  float cq[2];
  {
    const bool hi = (lane & 4) != 0;
    float s0 = hi ? bq[0] : bq[2];
    float s1 = hi ? bq[1] : bq[3];
    float k0 = hi ? bq[2] : bq[0];
    float k1 = hi ? bq[3] : bq[1];
    cq[0] = k0 + __shfl_xor(s0, 4);
    cq[1] = k1 + __shfl_xor(s1, 4);
  }
  float r;
  {
    const bool hi = (lane & 8) != 0;
    float send = hi ? cq[0] : cq[1];
    float keep = hi ? cq[1] : cq[0];
    r = keep + __shfl_xor(send, 8);
  }
  r += __shfl_xor(r, 16);
  r += __shfl_xor(r, 32);
  return r;
}

__device__ __forceinline__ void block_fold16(const float p[K1], float* wb, float* tb,
                                             int lane, int wv, int tid){
  float r = wave_fold16(p, lane);
  if (lane < 16) wb[wv * K1 + fold_col(lane)] = r;
  __syncthreads();
  if (tid < 16){
    float t = 0.0f;
    #pragma unroll
    for (int q = 0; q < NW; ++q) t += wb[q * K1 + tid];
    tb[tid] = t;
  }
  __syncthreads();
}

// =====================  STAGE: stats, top-k, Gamma0, warm start  ============
__global__ __launch_bounds__(NT, 2) void k_stage(
    const float* __restrict__ scores, const float* __restrict__ taup,
    const float* __restrict__ w1, const float* __restrict__ w2,
    unsigned* __restrict__ ws){
  const int b = blockIdx.x;
  const int tid = threadIdx.x;
  const int lane = tid & 63;
  const int wv = tid >> 6;
  float* wsf = reinterpret_cast<float*>(ws);

  __shared__ float scratch[NN];
  __shared__ float tk[KK];
  __shared__ __align__(16) float cbuf[K1];
  __shared__ float wbuf[NW * K1];
  __shared__ __align__(16) float xbuf[K1];
  __shared__ float rv[NW];
  __shared__ int ri[NW];
  __shared__ float rmn[NW];
  __shared__ unsigned sng[NW];
  __shared__ float statb[4];

  float raw[RPT];
  #pragma unroll
  for (int j = 0; j < RPT; ++j) raw[j] = scores[(size_t)b * NN + tid + NT * j];

  // ---- global min/max/neg + device spin-barrier ----
  {
    float mx = -INFINITY, mn = INFINITY; unsigned neg = 0u;
    #pragma unroll
    for (int j = 0; j < RPT; ++j){
      float v = raw[j];
      mx = fmaxf(mx, v);
      if (v == -INFINITY) neg = 1u; else mn = fminf(mn, v);
    }
    #pragma unroll
    for (int off = 32; off; off >>= 1){
      mx = fmaxf(mx, __shfl_xor(mx, off));
      mn = fminf(mn, __shfl_xor(mn, off));
      neg |= (unsigned)__shfl_xor((int)neg, off);
    }
    if (lane == 0){ rv[wv] = mx; rmn[wv] = mn; sng[wv] = neg; }
    __syncthreads();
    if (tid == 0){
      for (int q = 1; q < NW; ++q){
        mx = fmaxf(mx, rv[q]); mn = fminf(mn, rmn[q]); neg |= sng[q];
      }
      atomicMax(&ws[0], enc_f32(mx));
      atomicMin(&ws[5], enc_f32(mn));
      if (neg) atomicOr(&ws[1], 1u);
      __threadfence();
      atomicAdd(&ws[3], 1u);
      while (__hip_atomic_load(&ws[3], __ATOMIC_ACQUIRE, __HIP_MEMORY_SCOPE_AGENT) < (unsigned)BSZ)
        __builtin_amdgcn_s_sleep(2);
      statb[0] = dec_f32(__hip_atomic_load(&ws[0], __ATOMIC_RELAXED, __HIP_MEMORY_SCOPE_AGENT));
      statb[1] = dec_f32(__hip_atomic_load(&ws[5], __ATOMIC_RELAXED, __HIP_MEMORY_SCOPE_AGENT));
      statb[2] = __hip_atomic_load(&ws[1], __ATOMIC_RELAXED, __HIP_MEMORY_SCOPE_AGENT) ? 1.0f : 0.0f;
    }
    __syncthreads();
  }

  const float smax = statb[0];
  const float smin_raw = statb[1];
  const bool has_neg = statb[2] != 0.0f;
  const float filled = smin_raw - (smax - smin_raw);
  const float smin_eff = has_neg ? filled : smin_raw;
  const float cmax = fmaxf(fmaxf(smin_eff * smin_eff, smax * smax),
                           fmaxf((smin_eff - 15.0f) * (smin_eff - 15.0f),
                                 (smax - 15.0f) * (smax - 15.0f)));
  const float cinv = 1.0f / cmax;
  const float tauv = taup[0];
  const float inv_n = 1.0f / (float)NN;

  float sfix[RPT];
  #pragma unroll
  for (int j = 0; j < RPT; ++j){
    float v = raw[j];
    if (v == -INFINITY) v = filled;
    sfix[j] = v;
    scratch[tid + NT * j] = v;
  }
  __syncthreads();

  // ---- top-15 by iterative argmax ----
  for (int t = 0; t < KK; ++t){
    float bv = -INFINITY; int bi = NN;
    #pragma unroll
    for (int j = 0; j < RPT; ++j){
      int i = tid + NT * j;
      float v = scratch[i];
      if (v > bv){ bv = v; bi = i; }
    }
    #pragma unroll
    for (int off = 32; off; off >>= 1){
      float ov = __shfl_xor(bv, off);
      int oi = __shfl_xor(bi, off);
      if (ov > bv || (ov == bv && oi < bi)){ bv = ov; bi = oi; }
    }
    if (lane == 0){ rv[wv] = bv; ri[wv] = bi; }
    __syncthreads();
    if (tid == 0){
      for (int q = 1; q < NW; ++q){
        if (rv[q] > bv || (rv[q] == bv && ri[q] < bi)){ bv = rv[q]; bi = ri[q]; }
      }
      tk[t] = bv;
      scratch[bi] = -INFINITY;
    }
    __syncthreads();
  }

  // ---- Gamma0 column sums ----
  {
    float p[K1];
    float tkr[KK];
    #pragma unroll
    for (int c = 0; c < KK; ++c) tkr[c] = tk[c];
    #pragma unroll
    for (int c = 0; c < K1; ++c) p[c] = 0.0f;
    #pragma unroll
    for (int j = 0; j < RPT; ++j){
      float si = sfix[j];
      #pragma unroll
      for (int c = 0; c < KK; ++c){
        float z = fabsf(tkr[c] - si) / tauv;
        float raw1 = 1.0f / (1.0f + expf(z)) + SMALLC;
        p[c] += raw1;
      }
    }
    block_fold16(p, wbuf, cbuf, lane, wv, tid);
  }

  // ---- warm start x_r = <b, weight2[r,:]> ----
  {
    float p[K1];
    float tkr[KK], colr[KK];
    #pragma unroll
    for (int c = 0; c < KK; ++c){ tkr[c] = tk[c]; colr[c] = cbuf[c]; }
    #pragma unroll
    for (int c = 0; c < K1; ++c) p[c] = 0.0f;
    #pragma unroll
    for (int j = 0; j < RPT; ++j){
      int i = tid + NT * j;
      float si = sfix[j];
      float bb[K1];
      float rowpart = 0.0f;
      #pragma unroll
      for (int c = 0; c < KK; ++c){
        float d = si - (float)(KK - c);
        float Cc = d * d * cinv;
        float z = fabsf(tkr[c] - si) / tauv;
        float raw1 = 1.0f / (1.0f + expf(z)) + SMALLC;
        float g0 = (raw1 / colr[c]) * inv_n;
        rowpart += g0;
        bb[c] = Cc + EPSI * logf(g0);
      }
      {
        float Cc = si * si * cinv;
        float g0l = fminf(fmaxf(inv_n - rowpart, SMALLC), 1.0f - SMALLC);
        bb[KK] = Cc + EPSI * logf(g0l);
      }
      #pragma unroll
      for (int r = 0; r < 5; ++r){
        const float4* wp = (const float4*)(w2 + (size_t)r * W2STRIDE + (size_t)i * K1);
        float4 a0 = wp[0], a1 = wp[1], a2 = wp[2], a3 = wp[3];
        float acc = p[r];
        acc += bb[0] * a0.x + bb[1] * a0.y + bb[2] * a0.z + bb[3] * a0.w;
        acc += bb[4] * a1.x + bb[5] * a1.y + bb[6] * a1.z + bb[7] * a1.w;
        acc += bb[8] * a2.x + bb[9] * a2.y + bb[10] * a2.z + bb[11] * a2.w;
        acc += bb[12] * a3.x + bb[13] * a3.y + bb[14] * a3.z + bb[15] * a3.w;
        p[r] = acc;
      }
    }
    block_fold16(p, wbuf, xbuf, lane, wv, tid);
  }

  // ---- store per-row artifacts for the loop kernel ----
  if (tid < K1){
    float v0c;
    if (tid < KK){
      float g = 0.0f;
      #pragma unroll
      for (int r = 0; r < 5; ++r) g += xbuf[r] * w1[(size_t)(NN + tid) * 5 + r];
      v0c = expf(g * 10.0f);
    } else {
      v0c = 1.0f;
    }
    wsf[WS_VT0 + b * K1 + tid] = v0c;
    wsf[WS_CLO + b * K1 + tid] = cbuf[tid];
    if (tid < KK) wsf[WS_TKO + b * K1 + tid] = tk[tid];
  }
  if (b == 0 && tid == 0){ wsf[6] = filled; wsf[7] = cinv; }
}

// =====================  LOOP: 2 blocks per row, paired via L2  ==============
__global__ __launch_bounds__(NT, 2) void k_loop(
    const float* __restrict__ scores, const float* __restrict__ taup,
    float* __restrict__ out, unsigned* __restrict__ ws){
  const int B = blockIdx.x;
  const int h = (B >> 3) & 1;                      // half of the row
  const int row = ((B >> 4) << 3) | (B & 7);       // pair-mates B, B^8 share XCD (%8 heuristic)
  const int tid = threadIdx.x;
  const int lane = tid & 63;
  const int wv = tid >> 6;
  float* wsf = reinterpret_cast<float*>(ws);

  __shared__ __align__(16) float wbufT[2][K1 * TS];
  __shared__ __align__(16) float wvt[NW * K1];
  __shared__ float rv[NW];

  const float filled = wsf[6];
  const float cinv = wsf[7];
  const float tauv = taup[0];
  const float inv_n = 1.0f / (float)NN;

  float sfix[4];
  #pragma unroll
  for (int j = 0; j < 4; ++j){
    float v = scores[(size_t)row * NN + h * 2048 + tid + NT * j];
    if (v == -INFINITY) v = filled;
    sfix[j] = v;
  }

  float E[4][K1];
  #pragma unroll
  for (int j = 0; j < 4; ++j){
    #pragma unroll
    for (int c = 0; c < K1; ++c){
      float d = sfix[j] - (float)(KK - c);
      E[j][c] = expf(d * d * (-10.0f * cinv));
    }
  }

  float vt[K1];
  #pragma unroll
  for (int c = 0; c < K1; ++c) vt[c] = wsf[WS_VT0 + row * K1 + c];

  float* ps_base = wsf + WS_PSL + (size_t)row * 64;  // [phase][half][16]
  unsigned* fl = ws + WS_FLG + row * 4;              // [phase*2+half]
  const float nmul = ((lane & 15) < KK) ? 1.0f : 4081.0f;  // nu_c * NN

  float t[4];
  #pragma unroll 1
  for (int it = 0; it < NITER; ++it){
    const int ph = it & 1;
    #pragma unroll
    for (int j = 0; j < 4; ++j){
      float Hj = E[j][0] * vt[0];
      #pragma unroll
      for (int c = 1; c < K1; ++c) Hj = fmaf(E[j][c], vt[c], Hj);
      t[j] = __builtin_amdgcn_rcpf(Hj);
    }
    float p[K1];
    #pragma unroll
    for (int c = 0; c < K1; ++c){
      float a = E[0][c] * t[0];
      a = fmaf(E[1][c], t[1], a);
      a = fmaf(E[2][c], t[2], a);
      p[c] = fmaf(E[3][c], t[3], a);
    }
    float r = wave_fold16(p, lane);
    if (lane < 16) wbufT[ph][fold_col(lane) * TS + wv] = r;
    __syncthreads();
    float own;
    {
      const float* wp = &wbufT[ph][(lane & 15) * TS];
      float4 a4 = *(const float4*)wp;
      float4 b4 = *(const float4*)(wp + 4);
      own = ((a4.x + a4.y) + (a4.z + a4.w)) + ((b4.x + b4.y) + (b4.z + b4.w));
    }
    float* ps_own = ps_base + (ph * 2 + h) * 16;
    float* ps_oth = ps_base + (ph * 2 + (1 - h)) * 16;
    if (wv == 0){
      if (lane < 16)
        __hip_atomic_store(&ps_own[lane & 15], own, __ATOMIC_RELAXED, __HIP_MEMORY_SCOPE_AGENT);
      __threadfence();
      if (lane == 0)
        __hip_atomic_store(&fl[ph * 2 + h], (unsigned)(it + 1), __ATOMIC_RELEASE, __HIP_MEMORY_SCOPE_AGENT);
    }
    while (__hip_atomic_load(&fl[ph * 2 + (1 - h)], __ATOMIC_ACQUIRE, __HIP_MEMORY_SCOPE_AGENT) < (unsigned)(it + 1))
      __builtin_amdgcn_s_sleep(1);
    float oth = __hip_atomic_load(&ps_oth[lane & 15], __ATOMIC_RELAXED, __HIP_MEMORY_SCOPE_AGENT);
    float nv = nmul * __builtin_amdgcn_rcpf(own + oth);   // a+b bitwise == b+a: both halves agree
    if (lane < 16) wvt[wv * K1 + (lane & 15)] = nv;
    // same-wave LDS write->read: compiler inserts lgkmcnt wait; no barrier.
    float4 v0 = *(const float4*)&wvt[wv * K1 + 0];
    float4 v1 = *(const float4*)&wvt[wv * K1 + 4];
    float4 v2 = *(const float4*)&wvt[wv * K1 + 8];
    float4 v3 = *(const float4*)&wvt[wv * K1 + 12];
    vt[0] = v0.x; vt[1] = v0.y; vt[2] = v0.z; vt[3] = v0.w;
    vt[4] = v1.x; vt[5] = v1.y; vt[6] = v1.z; vt[7] = v1.w;
    vt[8] = v2.x; vt[9] = v2.y; vt[10] = v2.z; vt[11] = v2.w;
    vt[12] = v3.x; vt[13] = v3.y; vt[14] = v3.z; vt[15] = v3.w;
  }

  // ---- epilogue ----
  float tkr[KK], colr[KK];
  #pragma unroll
  for (int c = 0; c < KK; ++c) tkr[c] = wsf[WS_TKO + row * K1 + c];
  #pragma unroll
  for (int c = 0; c < KK; ++c) colr[c] = wsf[WS_CLO + row * K1 + c];
  float nrm = 0.0f;
  #pragma unroll
  for (int j = 0; j < 4; ++j){
    int gi = h * 2048 + tid + NT * j;
    float si = sfix[j];
    float tt = t[j] * inv_n;
    float rowpart = 0.0f;
    float* op = out + ((size_t)row * NN + gi) * KK;
    #pragma unroll
    for (int c = 0; c < KK; ++c){
      float gam = E[j][c] * tt * vt[c];
      float z = fabsf(tkr[c] - si) / tauv;
      float raw1 = 1.0f / (1.0f + expf(z)) + SMALLC;
      float g0 = (raw1 / colr[c]) * inv_n;
      rowpart += g0;
      float d = gam - g0;
      nrm += d * d;
      op[c] = gam * (float)NN;
    }
    {
      float gam = E[j][KK] * tt * vt[KK];
      float g0l = fminf(fmaxf(inv_n - rowpart, SMALLC), 1.0f - SMALLC);
      float d = gam - g0l;
      nrm += d * d;
    }
  }
  #pragma unroll
  for (int off = 32; off; off >>= 1) nrm += __shfl_xor(nrm, off);
  if (lane == 0) rv[wv] = nrm;
  __syncthreads();
  if (tid == 0){
    float s = 0.0f;
    for (int q = 0; q < NW; ++q) s += rv[q];
    atomicAdd(wsf + 2, s);
    __threadfence();
    unsigned prev = atomicAdd(&ws[4], 1u);
    if (prev == 255u){
      float n2 = __hip_atomic_load(wsf + 2, __ATOMIC_RELAXED, __HIP_MEMORY_SCOPE_AGENT);
      out[OUT_A_ELEMS] = sqrtf(n2);
    }
  }
}

extern "C" void kernel_launch(void* const* d_in, const int* in_sizes, int n_in,
                              void* d_out, int out_size, void* d_ws, size_t ws_size,
                              hipStream_t stream){
  const float* scores = (const float*)d_in[0];
  const float* tau    = (const float*)d_in[1];
  const float* w1     = (const float*)d_in[2];  // (4111, 5) row-major
  const float* w2     = (const float*)d_in[3];  // (5, 65536) row-major
  float* out = (float*)d_out;
  unsigned* ws = (unsigned*)d_ws;

  hipMemsetAsync(ws, 0x00, WS_TOT * 4, stream);
  hipMemsetAsync((char*)ws + 20, 0xFF, 4, stream);   // min_enc

  k_stage<<<BSZ, NT, 0, stream>>>(scores, tau, w1, w2, ws);
  k_loop<<<2 * BSZ, NT, 0, stream>>>(scores, tau, out, ws);
}

// Round 5
// 452.755 us; speedup vs baseline: 19.8551x; 19.8551x over previous
//
#include <hip/hip_runtime.h>
#include <math.h>

#define KK 15
#define K1 16
#define NN 4096
#define BSZ 128
#define NT 512
#define RPT 8          // rows per thread = NN/NT
#define NPAIR 4        // packed row pairs per thread
#define NW 8           // waves per block
#define EPSI 0.1f
#define SMALLC 1e-20f
#define NITER 200
#define W2STRIDE 65536
#define OUT_A_ELEMS (BSZ * NN * KK)
#define TS 20          // wbufT row stride in floats

typedef __attribute__((ext_vector_type(2))) float f2;
__device__ __forceinline__ f2 pk_fma(f2 a, f2 b, f2 c){
  return __builtin_elementwise_fma(a, b, c);
}

// ---------- sortable float <-> uint encoding for atomic min/max ----------
__device__ __forceinline__ unsigned enc_f32(float f){
  unsigned u = __float_as_uint(f);
  return (u & 0x80000000u) ? ~u : (u | 0x80000000u);
}
__device__ __forceinline__ float dec_f32(unsigned e){
  unsigned u = (e & 0x80000000u) ? (e ^ 0x80000000u) : ~e;
  return __uint_as_float(u);
}

// ws layout (uint32): [0]=max_enc(0) [1]=neg_flag(0) [2]=norm^2 f32(0)
//                     [3]=arrive(0) [4]=done(0) [5]=min_enc(0xFFFFFFFF)

// ---------- 16-column lane-fold reduction ----------
__device__ __forceinline__ int fold_col(int lane){
  int l = lane & 15;
  return ((l & 1) << 3) | ((l & 2) << 1) | ((l & 4) >> 1) | ((l & 8) >> 3);
}

__device__ __forceinline__ float wave_fold16(const float p[K1], int lane){
  float a[8];
  {
    const bool hi = (lane & 1) != 0;
    #pragma unroll
    for (int j = 0; j < 8; ++j){
      float send = hi ? p[j] : p[j + 8];
      float keep = hi ? p[j + 8] : p[j];
      a[j] = keep + __shfl_xor(send, 1);
    }
  }
  float bq[4];
  {
    const bool hi = (lane & 2) != 0;
    #pragma unroll
    for (int j = 0; j < 4; ++j){
      float send = hi ? a[j] : a[j + 4];
      float keep = hi ? a[j + 4] : a[j];
      bq[j] = keep + __shfl_xor(send, 2);
    }
  }
  float cq[2];
  {
    const bool hi = (lane & 4) != 0;
    float s0 = hi ? bq[0] : bq[2];
    float s1 = hi ? bq[1] : bq[3];
    float k0 = hi ? bq[2] : bq[0];
    float k1 = hi ? bq[3] : bq[1];
    cq[0] = k0 + __shfl_xor(s0, 4);
    cq[1] = k1 + __shfl_xor(s1, 4);
  }
  float r;
  {
    const bool hi = (lane & 8) != 0;
    float send = hi ? cq[0] : cq[1];
    float keep = hi ? cq[1] : cq[0];
    r = keep + __shfl_xor(send, 8);
  }
  r += __shfl_xor(r, 16);
  r += __shfl_xor(r, 32);
  return r;
}

__device__ __forceinline__ void block_fold16(const float p[K1], float* wb, float* tb,
                                             int lane, int wv, int tid){
  float r = wave_fold16(p, lane);
  if (lane < 16) wb[wv * K1 + fold_col(lane)] = r;
  __syncthreads();
  if (tid < 16){
    float t = 0.0f;
    #pragma unroll
    for (int q = 0; q < NW; ++q) t += wb[q * K1 + tid];
    tb[tid] = t;
  }
  __syncthreads();
}

__global__ __launch_bounds__(NT, 2) void k_main(
    const float* __restrict__ scores, const float* __restrict__ taup,
    const float* __restrict__ w1, const float* __restrict__ w2,
    float* __restrict__ out, unsigned* __restrict__ ws){
  const int b = blockIdx.x;
  const int tid = threadIdx.x;
  const int lane = tid & 63;
  const int wv = tid >> 6;

  __shared__ float scratch[NN];
  __shared__ float tk[KK];
  __shared__ __align__(16) float cbuf[K1];
  __shared__ float wbuf[NW * K1];
  __shared__ __align__(16) float xbuf[K1];
  __shared__ __align__(16) float wbufT[2][K1 * TS];
  __shared__ __align__(16) float wvt[NW * K1];
  __shared__ float rv[NW];
  __shared__ int ri[NW];
  __shared__ float rmn[NW];
  __shared__ unsigned sng[NW];
  __shared__ float statb[4];

  // ---- load raw row ----
  float raw[RPT];
  #pragma unroll
  for (int j = 0; j < RPT; ++j) raw[j] = scores[(size_t)b * NN + tid + NT * j];

  // ---- fused global min/max/neg + device spin-barrier ----
  {
    float mx = -INFINITY, mn = INFINITY; unsigned neg = 0u;
    #pragma unroll
    for (int j = 0; j < RPT; ++j){
      float v = raw[j];
      mx = fmaxf(mx, v);
      if (v == -INFINITY) neg = 1u; else mn = fminf(mn, v);
    }
    #pragma unroll
    for (int off = 32; off; off >>= 1){
      mx = fmaxf(mx, __shfl_xor(mx, off));
      mn = fminf(mn, __shfl_xor(mn, off));
      neg |= (unsigned)__shfl_xor((int)neg, off);
    }
    if (lane == 0){ rv[wv] = mx; rmn[wv] = mn; sng[wv] = neg; }
    __syncthreads();
    if (tid == 0){
      for (int q = 1; q < NW; ++q){
        mx = fmaxf(mx, rv[q]); mn = fminf(mn, rmn[q]); neg |= sng[q];
      }
      atomicMax(&ws[0], enc_f32(mx));
      atomicMin(&ws[5], enc_f32(mn));
      if (neg) atomicOr(&ws[1], 1u);
      __threadfence();
      atomicAdd(&ws[3], 1u);
      while (__hip_atomic_load(&ws[3], __ATOMIC_ACQUIRE, __HIP_MEMORY_SCOPE_AGENT) < (unsigned)BSZ)
        __builtin_amdgcn_s_sleep(2);
      statb[0] = dec_f32(__hip_atomic_load(&ws[0], __ATOMIC_RELAXED, __HIP_MEMORY_SCOPE_AGENT));
      statb[1] = dec_f32(__hip_atomic_load(&ws[5], __ATOMIC_RELAXED, __HIP_MEMORY_SCOPE_AGENT));
      statb[2] = __hip_atomic_load(&ws[1], __ATOMIC_RELAXED, __HIP_MEMORY_SCOPE_AGENT) ? 1.0f : 0.0f;
    }
    __syncthreads();
  }

  const float smax = statb[0];
  const float smin_raw = statb[1];
  const bool has_neg = statb[2] != 0.0f;
  const float filled = smin_raw - (smax - smin_raw);
  const float smin_eff = has_neg ? filled : smin_raw;
  const float cmax = fmaxf(fmaxf(smin_eff * smin_eff, smax * smax),
                           fmaxf((smin_eff - 15.0f) * (smin_eff - 15.0f),
                                 (smax - 15.0f) * (smax - 15.0f)));
  const float cinv = 1.0f / cmax;
  const float tauv = taup[0];
  const float inv_n = 1.0f / (float)NN;   // 2^-12, exact

  // ---- fixed s values: pairs in regs (constant-indexed only); scratch for top-k ----
  f2 sf2[NPAIR];
  #pragma unroll
  for (int q = 0; q < NPAIR; ++q){
    float v0 = raw[2 * q];     if (v0 == -INFINITY) v0 = filled;
    float v1 = raw[2 * q + 1]; if (v1 == -INFINITY) v1 = filled;
    sf2[q].x = v0; sf2[q].y = v1;
    scratch[tid + NT * (2 * q)] = v0;
    scratch[tid + NT * (2 * q + 1)] = v1;
  }
  __syncthreads();

  // ---- top-15 by iterative argmax ----
  for (int t = 0; t < KK; ++t){
    float bv = -INFINITY; int bi = NN;
    #pragma unroll
    for (int j = 0; j < RPT; ++j){
      int i = tid + NT * j;
      float v = scratch[i];
      if (v > bv){ bv = v; bi = i; }
    }
    #pragma unroll
    for (int off = 32; off; off >>= 1){
      float ov = __shfl_xor(bv, off);
      int oi = __shfl_xor(bi, off);
      if (ov > bv || (ov == bv && oi < bi)){ bv = ov; bi = oi; }
    }
    if (lane == 0){ rv[wv] = bv; ri[wv] = bi; }
    __syncthreads();
    if (tid == 0){
      for (int q = 1; q < NW; ++q){
        if (rv[q] > bv || (rv[q] == bv && ri[q] < bi)){ bv = rv[q]; bi = ri[q]; }
      }
      tk[t] = bv;
      scratch[bi] = -INFINITY;
    }
    __syncthreads();
  }

  // ---- Gamma0 column sums ----
  {
    float p[K1];
    float tkr[KK];
    #pragma unroll
    for (int c = 0; c < KK; ++c) tkr[c] = tk[c];
    #pragma unroll
    for (int c = 0; c < K1; ++c) p[c] = 0.0f;
    #pragma unroll
    for (int j = 0; j < RPT; ++j){
      float si = (j & 1) ? sf2[j / 2].y : sf2[j / 2].x;   // j literal after unroll
      #pragma unroll
      for (int c = 0; c < KK; ++c){
        float z = fabsf(tkr[c] - si) / tauv;
        float raw1 = 1.0f / (1.0f + expf(z)) + SMALLC;
        p[c] += raw1;
      }
    }
    block_fold16(p, wbuf, cbuf, lane, wv, tid);
  }

  // ---- warm start x_r = <b, weight2[r,:]> ----
  {
    float p[K1];
    float tkr[KK], colr[KK];
    #pragma unroll
    for (int c = 0; c < KK; ++c){ tkr[c] = tk[c]; colr[c] = cbuf[c]; }
    #pragma unroll
    for (int c = 0; c < K1; ++c) p[c] = 0.0f;
    #pragma unroll
    for (int j = 0; j < RPT; ++j){
      int i = tid + NT * j;
      float si = (j & 1) ? sf2[j / 2].y : sf2[j / 2].x;
      float bb[K1];
      float rowpart = 0.0f;
      #pragma unroll
      for (int c = 0; c < KK; ++c){
        float d = si - (float)(KK - c);
        float Cc = d * d * cinv;
        float z = fabsf(tkr[c] - si) / tauv;
        float raw1 = 1.0f / (1.0f + expf(z)) + SMALLC;
        float g0 = (raw1 / colr[c]) * inv_n;
        rowpart += g0;
        bb[c] = Cc + EPSI * logf(g0);
      }
      {
        float Cc = si * si * cinv;  // anchor 0 for c=15
        float g0l = fminf(fmaxf(inv_n - rowpart, SMALLC), 1.0f - SMALLC);
        bb[KK] = Cc + EPSI * logf(g0l);
      }
      #pragma unroll
      for (int r = 0; r < 5; ++r){
        const float4* wp = (const float4*)(w2 + (size_t)r * W2STRIDE + (size_t)i * K1);
        float4 a0 = wp[0], a1 = wp[1], a2 = wp[2], a3 = wp[3];
        float acc = p[r];
        acc += bb[0] * a0.x + bb[1] * a0.y + bb[2] * a0.z + bb[3] * a0.w;
        acc += bb[4] * a1.x + bb[5] * a1.y + bb[6] * a1.z + bb[7] * a1.w;
        acc += bb[8] * a2.x + bb[9] * a2.y + bb[10] * a2.z + bb[11] * a2.w;
        acc += bb[12] * a3.x + bb[13] * a3.y + bb[14] * a3.z + bb[15] * a3.w;
        p[r] = acc;
      }
    }
    block_fold16(p, wbuf, xbuf, lane, wv, tid);
  }

  // ---- vt init ----
  float vt[K1];
  {
    float xv[5];
    #pragma unroll
    for (int r = 0; r < 5; ++r) xv[r] = xbuf[r];
    #pragma unroll
    for (int c = 0; c < KK; ++c){
      float g = 0.0f;
      #pragma unroll
      for (int r = 0; r < 5; ++r) g += xv[r] * w1[(size_t)(NN + c) * 5 + r];
      vt[c] = expf(g * 10.0f);
    }
    vt[KK] = 1.0f;
  }

  // ---- E in registers, packed over row pairs (constant indices ONLY) ----
  f2 E2[NPAIR][K1];
  #pragma unroll
  for (int q = 0; q < NPAIR; ++q){
    #pragma unroll
    for (int c = 0; c < K1; ++c){
      float a = (float)(KK - c);
      float d0 = sf2[q].x - a, d1 = sf2[q].y - a;
      f2 e;
      e.x = expf(d0 * d0 * (-10.0f * cinv));
      e.y = expf(d1 * d1 * (-10.0f * cinv));
      E2[q][c] = e;
    }
  }

  // ---- 200 Sinkhorn iterations (scaling form), one barrier per iteration ----
  f2 t2[NPAIR];
  const float nmul = ((lane & 15) < KK) ? 1.0f : 4081.0f;  // nu_c * NN
  #pragma unroll 1
  for (int it = 0; it < NITER; ++it){
    const int ph = it & 1;
    #pragma unroll
    for (int q = 0; q < NPAIR; ++q){
      f2 v0; v0.x = vt[0]; v0.y = vt[0];
      f2 h = E2[q][0] * v0;
      #pragma unroll
      for (int c = 1; c < K1; ++c){
        f2 vc; vc.x = vt[c]; vc.y = vt[c];
        h = pk_fma(E2[q][c], vc, h);
      }
      f2 t; t.x = __builtin_amdgcn_rcpf(h.x); t.y = __builtin_amdgcn_rcpf(h.y);
      t2[q] = t;
    }
    float p[K1];
    #pragma unroll
    for (int c = 0; c < K1; ++c){
      f2 acc = E2[0][c] * t2[0];
      acc = pk_fma(E2[1][c], t2[1], acc);
      acc = pk_fma(E2[2][c], t2[2], acc);
      acc = pk_fma(E2[3][c], t2[3], acc);
      p[c] = acc.x + acc.y;
    }
    float r = wave_fold16(p, lane);
    if (lane < 16) wbufT[ph][fold_col(lane) * TS + wv] = r;
    __syncthreads();
    {
      const float* wp = &wbufT[ph][(lane & 15) * TS];
      float4 a4 = *(const float4*)wp;
      float4 b4 = *(const float4*)(wp + 4);
      float t = ((a4.x + a4.y) + (a4.z + a4.w)) + ((b4.x + b4.y) + (b4.z + b4.w));
      float nv = nmul * __builtin_amdgcn_rcpf(t);
      if (lane < 16) wvt[wv * K1 + (lane & 15)] = nv;
      // same-wave LDS write->read: lgkmcnt ordering, no barrier needed.
      float4 v0 = *(const float4*)&wvt[wv * K1 + 0];
      float4 v1 = *(const float4*)&wvt[wv * K1 + 4];
      float4 v2 = *(const float4*)&wvt[wv * K1 + 8];
      float4 v3 = *(const float4*)&wvt[wv * K1 + 12];
      vt[0] = v0.x; vt[1] = v0.y; vt[2] = v0.z; vt[3] = v0.w;
      vt[4] = v1.x; vt[5] = v1.y; vt[6] = v1.z; vt[7] = v1.w;
      vt[8] = v2.x; vt[9] = v2.y; vt[10] = v2.z; vt[11] = v2.w;
      vt[12] = v3.x; vt[13] = v3.y; vt[14] = v3.z; vt[15] = v3.w;
    }
  }

  // ---- epilogue: per-pair, explicit .x/.y blocks (no dynamic indices) ----
  float nrm = 0.0f;
  {
    float tkr[KK], colr[KK];
    #pragma unroll
    for (int c = 0; c < KK; ++c){ tkr[c] = tk[c]; colr[c] = cbuf[c]; }
    #pragma unroll
    for (int q = 0; q < NPAIR; ++q){
      // element x: row j = 2q
      {
        int i = tid + NT * (2 * q);
        float si = sf2[q].x;
        float tt = t2[q].x * inv_n;
        float rowpart = 0.0f;
        float* op = out + (size_t)(b * NN + i) * KK;
        #pragma unroll
        for (int c = 0; c < KK; ++c){
          float gam = E2[q][c].x * tt * vt[c];
          float z = fabsf(tkr[c] - si) / tauv;
          float raw1 = 1.0f / (1.0f + expf(z)) + SMALLC;
          float g0 = (raw1 / colr[c]) * inv_n;
          rowpart += g0;
          float d = gam - g0;
          nrm += d * d;
          op[c] = gam * (float)NN;
        }
        {
          float gam = E2[q][KK].x * tt * vt[KK];
          float g0l = fminf(fmaxf(inv_n - rowpart, SMALLC), 1.0f - SMALLC);
          float d = gam - g0l;
          nrm += d * d;
        }
      }
      // element y: row j = 2q+1
      {
        int i = tid + NT * (2 * q + 1);
        float si = sf2[q].y;
        float tt = t2[q].y * inv_n;
        float rowpart = 0.0f;
        float* op = out + (size_t)(b * NN + i) * KK;
        #pragma unroll
        for (int c = 0; c < KK; ++c){
          float gam = E2[q][c].y * tt * vt[c];
          float z = fabsf(tkr[c] - si) / tauv;
          float raw1 = 1.0f / (1.0f + expf(z)) + SMALLC;
          float g0 = (raw1 / colr[c]) * inv_n;
          rowpart += g0;
          float d = gam - g0;
          nrm += d * d;
          op[c] = gam * (float)NN;
        }
        {
          float gam = E2[q][KK].y * tt * vt[KK];
          float g0l = fminf(fmaxf(inv_n - rowpart, SMALLC), 1.0f - SMALLC);
          float d = gam - g0l;
          nrm += d * d;
        }
      }
    }
  }
  #pragma unroll
  for (int off = 32; off; off >>= 1) nrm += __shfl_xor(nrm, off);
  if (lane == 0) rv[wv] = nrm;
  __syncthreads();
  if (tid == 0){
    float t = 0.0f;
    for (int q = 0; q < NW; ++q) t += rv[q];
    atomicAdd(reinterpret_cast<float*>(ws) + 2, t);
    __threadfence();
    unsigned prev = atomicAdd(&ws[4], 1u);
    if (prev == (unsigned)(BSZ - 1)){
      float n2 = __hip_atomic_load(reinterpret_cast<float*>(ws) + 2,
                                   __ATOMIC_RELAXED, __HIP_MEMORY_SCOPE_AGENT);
      out[OUT_A_ELEMS] = sqrtf(n2);
    }
  }
}

extern "C" void kernel_launch(void* const* d_in, const int* in_sizes, int n_in,
                              void* d_out, int out_size, void* d_ws, size_t ws_size,
                              hipStream_t stream){
  const float* scores = (const float*)d_in[0];
  const float* tau    = (const float*)d_in[1];
  const float* w1     = (const float*)d_in[2];  // (4111, 5) row-major
  const float* w2     = (const float*)d_in[3];  // (5, 65536) row-major
  float* out = (float*)d_out;
  unsigned* ws = (unsigned*)d_ws;

  // [0]=max_enc 0, [1]=neg 0, [2]=norm 0.f, [3]=arrive 0, [4]=done 0, [5]=min_enc FF
  hipMemsetAsync(ws, 0x00, 20, stream);
  hipMemsetAsync((char*)ws + 20, 0xFF, 4, stream);

  k_main<<<BSZ, NT, 0, stream>>>(scores, tau, w1, w2, out, ws);
}

// Round 6
// 251.666 us; speedup vs baseline: 35.7198x; 1.7990x over previous
//
#include <hip/hip_runtime.h>
#include <math.h>

#define KK 15
#define K1 16
#define NN 4096
#define BSZ 128
#define NT 1024
#define RPT 4          // rows per thread = NN/NT
#define NPAIR 2        // packed row pairs per thread
#define NW 16          // waves per block
#define EPSI 0.1f
#define SMALLC 1e-20f
#define NITER 200
#define W2STRIDE 65536
#define OUT_A_ELEMS (BSZ * NN * KK)
#define TS 20          // wbufT row stride in floats
#define CONV_REL 5e-7f

typedef __attribute__((ext_vector_type(2))) float f2;
__device__ __forceinline__ f2 pk_fma(f2 a, f2 b, f2 c){
  return __builtin_elementwise_fma(a, b, c);
}

// ---------- sortable float <-> uint encoding for atomic min/max ----------
__device__ __forceinline__ unsigned enc_f32(float f){
  unsigned u = __float_as_uint(f);
  return (u & 0x80000000u) ? ~u : (u | 0x80000000u);
}
__device__ __forceinline__ float dec_f32(unsigned e){
  unsigned u = (e & 0x80000000u) ? (e ^ 0x80000000u) : ~e;
  return __uint_as_float(u);
}

// ws layout (uint32): [0]=max_enc(0) [1]=neg_flag(0) [2]=norm^2 f32(0)
//                     [3]=arrive(0) [4]=done(0) [5]=min_enc(0xFFFFFFFF)

// ---------- 16-column lane-fold reduction ----------
__device__ __forceinline__ int fold_col(int lane){
  int l = lane & 15;
  return ((l & 1) << 3) | ((l & 2) << 1) | ((l & 4) >> 1) | ((l & 8) >> 3);
}

__device__ __forceinline__ float wave_fold16(const float p[K1], int lane){
  float a[8];
  {
    const bool hi = (lane & 1) != 0;
    #pragma unroll
    for (int j = 0; j < 8; ++j){
      float send = hi ? p[j] : p[j + 8];
      float keep = hi ? p[j + 8] : p[j];
      a[j] = keep + __shfl_xor(send, 1);
    }
  }
  float bq[4];
  {
    const bool hi = (lane & 2) != 0;
    #pragma unroll
    for (int j = 0; j < 4; ++j){
      float send = hi ? a[j] : a[j + 4];
      float keep = hi ? a[j + 4] : a[j];
      bq[j] = keep + __shfl_xor(send, 2);
    }
  }
  float cq[2];
  {
    const bool hi = (lane & 4) != 0;
    float s0 = hi ? bq[0] : bq[2];
    float s1 = hi ? bq[1] : bq[3];
    float k0 = hi ? bq[2] : bq[0];
    float k1 = hi ? bq[3] : bq[1];
    cq[0] = k0 + __shfl_xor(s0, 4);
    cq[1] = k1 + __shfl_xor(s1, 4);
  }
  float r;
  {
    const bool hi = (lane & 8) != 0;
    float send = hi ? cq[0] : cq[1];
    float keep = hi ? cq[1] : cq[0];
    r = keep + __shfl_xor(send, 8);
  }
  r += __shfl_xor(r, 16);
  r += __shfl_xor(r, 32);
  return r;
}

__device__ __forceinline__ void block_fold16(const float p[K1], float* wb, float* tb,
                                             int lane, int wv, int tid){
  float r = wave_fold16(p, lane);
  if (lane < 16) wb[wv * K1 + fold_col(lane)] = r;
  __syncthreads();
  if (tid < 16){
    float t = 0.0f;
    #pragma unroll
    for (int q = 0; q < NW; ++q) t += wb[q * K1 + tid];
    tb[tid] = t;
  }
  __syncthreads();
}

__global__ __launch_bounds__(NT, 1) void k_main(
    const float* __restrict__ scores, const float* __restrict__ taup,
    const float* __restrict__ w1, const float* __restrict__ w2,
    float* __restrict__ out, unsigned* __restrict__ ws){
  const int b = blockIdx.x;
  const int tid = threadIdx.x;
  const int lane = tid & 63;
  const int wv = tid >> 6;

  __shared__ float scratch[NN];
  __shared__ float tk[KK];
  __shared__ __align__(16) float cbuf[K1];
  __shared__ float wbuf[NW * K1];
  __shared__ __align__(16) float xbuf[K1];
  __shared__ __align__(16) float wbufT[2][K1 * TS];
  __shared__ __align__(16) float wvt[NW * K1];
  __shared__ float rv[NW];
  __shared__ int ri[NW];
  __shared__ float rmn[NW];
  __shared__ unsigned sng[NW];
  __shared__ float statb[4];

  // ---- load raw row ----
  float raw[RPT];
  #pragma unroll
  for (int j = 0; j < RPT; ++j) raw[j] = scores[(size_t)b * NN + tid + NT * j];

  // ---- fused global min/max/neg + device spin-barrier ----
  {
    float mx = -INFINITY, mn = INFINITY; unsigned neg = 0u;
    #pragma unroll
    for (int j = 0; j < RPT; ++j){
      float v = raw[j];
      mx = fmaxf(mx, v);
      if (v == -INFINITY) neg = 1u; else mn = fminf(mn, v);
    }
    #pragma unroll
    for (int off = 32; off; off >>= 1){
      mx = fmaxf(mx, __shfl_xor(mx, off));
      mn = fminf(mn, __shfl_xor(mn, off));
      neg |= (unsigned)__shfl_xor((int)neg, off);
    }
    if (lane == 0){ rv[wv] = mx; rmn[wv] = mn; sng[wv] = neg; }
    __syncthreads();
    if (tid == 0){
      for (int q = 1; q < NW; ++q){
        mx = fmaxf(mx, rv[q]); mn = fminf(mn, rmn[q]); neg |= sng[q];
      }
      atomicMax(&ws[0], enc_f32(mx));
      atomicMin(&ws[5], enc_f32(mn));
      if (neg) atomicOr(&ws[1], 1u);
      __threadfence();
      atomicAdd(&ws[3], 1u);
      while (__hip_atomic_load(&ws[3], __ATOMIC_ACQUIRE, __HIP_MEMORY_SCOPE_AGENT) < (unsigned)BSZ)
        __builtin_amdgcn_s_sleep(2);
      statb[0] = dec_f32(__hip_atomic_load(&ws[0], __ATOMIC_RELAXED, __HIP_MEMORY_SCOPE_AGENT));
      statb[1] = dec_f32(__hip_atomic_load(&ws[5], __ATOMIC_RELAXED, __HIP_MEMORY_SCOPE_AGENT));
      statb[2] = __hip_atomic_load(&ws[1], __ATOMIC_RELAXED, __HIP_MEMORY_SCOPE_AGENT) ? 1.0f : 0.0f;
    }
    __syncthreads();
  }

  const float smax = statb[0];
  const float smin_raw = statb[1];
  const bool has_neg = statb[2] != 0.0f;
  const float filled = smin_raw - (smax - smin_raw);
  const float smin_eff = has_neg ? filled : smin_raw;
  const float cmax = fmaxf(fmaxf(smin_eff * smin_eff, smax * smax),
                           fmaxf((smin_eff - 15.0f) * (smin_eff - 15.0f),
                                 (smax - 15.0f) * (smax - 15.0f)));
  const float cinv = 1.0f / cmax;
  const float tauv = taup[0];
  const float inv_n = 1.0f / (float)NN;   // 2^-12, exact

  // ---- fixed s values: pairs in regs; scratch for top-k ----
  f2 sf2[NPAIR];
  #pragma unroll
  for (int q = 0; q < NPAIR; ++q){
    float v0 = raw[2 * q];     if (v0 == -INFINITY) v0 = filled;
    float v1 = raw[2 * q + 1]; if (v1 == -INFINITY) v1 = filled;
    sf2[q].x = v0; sf2[q].y = v1;
    scratch[tid + NT * (2 * q)] = v0;
    scratch[tid + NT * (2 * q + 1)] = v1;
  }
  __syncthreads();

  // ---- top-15 by iterative argmax ----
  for (int t = 0; t < KK; ++t){
    float bv = -INFINITY; int bi = NN;
    #pragma unroll
    for (int j = 0; j < RPT; ++j){
      int i = tid + NT * j;
      float v = scratch[i];
      if (v > bv){ bv = v; bi = i; }
    }
    #pragma unroll
    for (int off = 32; off; off >>= 1){
      float ov = __shfl_xor(bv, off);
      int oi = __shfl_xor(bi, off);
      if (ov > bv || (ov == bv && oi < bi)){ bv = ov; bi = oi; }
    }
    if (lane == 0){ rv[wv] = bv; ri[wv] = bi; }
    __syncthreads();
    if (tid == 0){
      for (int q = 1; q < NW; ++q){
        if (rv[q] > bv || (rv[q] == bv && ri[q] < bi)){ bv = rv[q]; bi = ri[q]; }
      }
      tk[t] = bv;
      scratch[bi] = -INFINITY;
    }
    __syncthreads();
  }

  // ---- Gamma0 column sums ----
  {
    float p[K1];
    float tkr[KK];
    #pragma unroll
    for (int c = 0; c < KK; ++c) tkr[c] = tk[c];
    #pragma unroll
    for (int c = 0; c < K1; ++c) p[c] = 0.0f;
    #pragma unroll
    for (int j = 0; j < RPT; ++j){
      float si = (j & 1) ? sf2[j / 2].y : sf2[j / 2].x;
      #pragma unroll
      for (int c = 0; c < KK; ++c){
        float z = fabsf(tkr[c] - si) / tauv;
        float raw1 = 1.0f / (1.0f + expf(z)) + SMALLC;
        p[c] += raw1;
      }
    }
    block_fold16(p, wbuf, cbuf, lane, wv, tid);
  }

  // ---- warm start x_r = <b, weight2[r,:]> ----
  {
    float p[K1];
    float tkr[KK], colr[KK];
    #pragma unroll
    for (int c = 0; c < KK; ++c){ tkr[c] = tk[c]; colr[c] = cbuf[c]; }
    #pragma unroll
    for (int c = 0; c < K1; ++c) p[c] = 0.0f;
    #pragma unroll
    for (int j = 0; j < RPT; ++j){
      int i = tid + NT * j;
      float si = (j & 1) ? sf2[j / 2].y : sf2[j / 2].x;
      float bb[K1];
      float rowpart = 0.0f;
      #pragma unroll
      for (int c = 0; c < KK; ++c){
        float d = si - (float)(KK - c);
        float Cc = d * d * cinv;
        float z = fabsf(tkr[c] - si) / tauv;
        float raw1 = 1.0f / (1.0f + expf(z)) + SMALLC;
        float g0 = (raw1 / colr[c]) * inv_n;
        rowpart += g0;
        bb[c] = Cc + EPSI * logf(g0);
      }
      {
        float Cc = si * si * cinv;  // anchor 0 for c=15
        float g0l = fminf(fmaxf(inv_n - rowpart, SMALLC), 1.0f - SMALLC);
        bb[KK] = Cc + EPSI * logf(g0l);
      }
      #pragma unroll
      for (int r = 0; r < 5; ++r){
        const float4* wp = (const float4*)(w2 + (size_t)r * W2STRIDE + (size_t)i * K1);
        float4 a0 = wp[0], a1 = wp[1], a2 = wp[2], a3 = wp[3];
        float acc = p[r];
        acc += bb[0] * a0.x + bb[1] * a0.y + bb[2] * a0.z + bb[3] * a0.w;
        acc += bb[4] * a1.x + bb[5] * a1.y + bb[6] * a1.z + bb[7] * a1.w;
        acc += bb[8] * a2.x + bb[9] * a2.y + bb[10] * a2.z + bb[11] * a2.w;
        acc += bb[12] * a3.x + bb[13] * a3.y + bb[14] * a3.z + bb[15] * a3.w;
        p[r] = acc;
      }
    }
    block_fold16(p, wbuf, xbuf, lane, wv, tid);
  }

  // ---- vt init: vt_c = B_c * exp(g_c/eps); vt[15] = 1 ----
  // Factorization: E_jc = P_j * x_j^c * B_c, x_j = exp(-20 s_j/cmax),
  // B_c = exp(-10 (15-c)^2/cmax). P,B cancel in the iteration (t=P*u, vt=B*v);
  // B appears only in the init. Gamma = x^c * t * vt.
  float vt[K1];
  {
    float xv[5];
    #pragma unroll
    for (int r = 0; r < 5; ++r) xv[r] = xbuf[r];
    #pragma unroll
    for (int c = 0; c < KK; ++c){
      float g = 0.0f;
      #pragma unroll
      for (int r = 0; r < 5; ++r) g += xv[r] * w1[(size_t)(NN + c) * 5 + r];
      float Bc = expf(-10.0f * cinv * (float)((KK - c) * (KK - c)));
      vt[c] = Bc * expf(g * 10.0f);
    }
    vt[KK] = 1.0f;
  }

  // ---- x per row pair ----
  f2 x2[NPAIR];
  #pragma unroll
  for (int q = 0; q < NPAIR; ++q){
    x2[q].x = expf(sf2[q].x * (-20.0f * cinv));
    x2[q].y = expf(sf2[q].y * (-20.0f * cinv));
  }

  // ---- Sinkhorn iterations: Horner row-sum + power-chain col partials,
  //      one barrier/iter, ulp-convergence exit ----
  f2 t2[NPAIR];
  const float nmul = ((lane & 15) < KK) ? 1.0f : 4081.0f;  // nu_c * NN
  #pragma unroll 1
  for (int it = 0; it < NITER; ++it){
    const int ph = it & 1;
    #pragma unroll
    for (int q = 0; q < NPAIR; ++q){
      f2 h; h.x = vt[KK]; h.y = vt[KK];
      #pragma unroll
      for (int c = KK - 1; c >= 0; --c){
        f2 vc; vc.x = vt[c]; vc.y = vt[c];
        h = pk_fma(h, x2[q], vc);
      }
      f2 t; t.x = __builtin_amdgcn_rcpf(h.x); t.y = __builtin_amdgcn_rcpf(h.y);
      t2[q] = t;
    }
    float p[K1];
    {
      f2 P2[K1];
      #pragma unroll
      for (int q = 0; q < NPAIR; ++q){
        f2 pw = t2[q];
        #pragma unroll
        for (int c = 0; c < K1; ++c){
          if (q == 0) P2[c] = pw; else P2[c] += pw;
          if (c < KK) pw = pw * x2[q];
        }
      }
      #pragma unroll
      for (int c = 0; c < K1; ++c) p[c] = P2[c].x + P2[c].y;
    }
    float r = wave_fold16(p, lane);
    if (lane < 16) wbufT[ph][fold_col(lane) * TS + wv] = r;
    __syncthreads();
    if (lane < 16){
      const float* wp = &wbufT[ph][lane * TS];
      float4 a4 = *(const float4*)wp;
      float4 b4 = *(const float4*)(wp + 4);
      float4 c4 = *(const float4*)(wp + 8);
      float4 d4 = *(const float4*)(wp + 12);
      float t = (((a4.x + a4.y) + (a4.z + a4.w)) + ((b4.x + b4.y) + (b4.z + b4.w)))
              + (((c4.x + c4.y) + (c4.z + c4.w)) + ((d4.x + d4.y) + (d4.z + d4.w)));
      wvt[wv * K1 + lane] = nmul * __builtin_amdgcn_rcpf(t);
    }
    // same-wave LDS write->read: lgkmcnt ordering, no barrier needed.
    float4 v0 = *(const float4*)&wvt[wv * K1 + 0];
    float4 v1 = *(const float4*)&wvt[wv * K1 + 4];
    float4 v2 = *(const float4*)&wvt[wv * K1 + 8];
    float4 v3 = *(const float4*)&wvt[wv * K1 + 12];
    float md = 0.0f;
    md = fmaxf(md, fabsf(v0.x - vt[0])  - CONV_REL * vt[0]);
    md = fmaxf(md, fabsf(v0.y - vt[1])  - CONV_REL * vt[1]);
    md = fmaxf(md, fabsf(v0.z - vt[2])  - CONV_REL * vt[2]);
    md = fmaxf(md, fabsf(v0.w - vt[3])  - CONV_REL * vt[3]);
    md = fmaxf(md, fabsf(v1.x - vt[4])  - CONV_REL * vt[4]);
    md = fmaxf(md, fabsf(v1.y - vt[5])  - CONV_REL * vt[5]);
    md = fmaxf(md, fabsf(v1.z - vt[6])  - CONV_REL * vt[6]);
    md = fmaxf(md, fabsf(v1.w - vt[7])  - CONV_REL * vt[7]);
    md = fmaxf(md, fabsf(v2.x - vt[8])  - CONV_REL * vt[8]);
    md = fmaxf(md, fabsf(v2.y - vt[9])  - CONV_REL * vt[9]);
    md = fmaxf(md, fabsf(v2.z - vt[10]) - CONV_REL * vt[10]);
    md = fmaxf(md, fabsf(v2.w - vt[11]) - CONV_REL * vt[11]);
    md = fmaxf(md, fabsf(v3.x - vt[12]) - CONV_REL * vt[12]);
    md = fmaxf(md, fabsf(v3.y - vt[13]) - CONV_REL * vt[13]);
    md = fmaxf(md, fabsf(v3.z - vt[14]) - CONV_REL * vt[14]);
    md = fmaxf(md, fabsf(v3.w - vt[15]) - CONV_REL * vt[15]);
    vt[0] = v0.x; vt[1] = v0.y; vt[2] = v0.z; vt[3] = v0.w;
    vt[4] = v1.x; vt[5] = v1.y; vt[6] = v1.z; vt[7] = v1.w;
    vt[8] = v2.x; vt[9] = v2.y; vt[10] = v2.z; vt[11] = v2.w;
    vt[12] = v3.x; vt[13] = v3.y; vt[14] = v3.z; vt[15] = v3.w;
    if (md <= 0.0f) break;    // uniform across block (bitwise-identical vt)
  }

  // ---- epilogue: Gamma = x^c * (inv_n*t) * vt; A = Gamma[:,:,:15]*n; norm^2 ----
  float nrm = 0.0f;
  {
    float tkr[KK], colr[KK];
    #pragma unroll
    for (int c = 0; c < KK; ++c){ tkr[c] = tk[c]; colr[c] = cbuf[c]; }
    #pragma unroll
    for (int q = 0; q < NPAIR; ++q){
      // element x: row j = 2q
      {
        int i = tid + NT * (2 * q);
        float si = sf2[q].x;
        float xj = x2[q].x;
        float pw = t2[q].x * inv_n;
        float rowpart = 0.0f;
        float* op = out + (size_t)(b * NN + i) * KK;
        #pragma unroll
        for (int c = 0; c < KK; ++c){
          float gam = pw * vt[c];
          pw *= xj;
          float z = fabsf(tkr[c] - si) / tauv;
          float raw1 = 1.0f / (1.0f + expf(z)) + SMALLC;
          float g0 = (raw1 / colr[c]) * inv_n;
          rowpart += g0;
          float d = gam - g0;
          nrm += d * d;
          op[c] = gam * (float)NN;
        }
        {
          float gam = pw * vt[KK];
          float g0l = fminf(fmaxf(inv_n - rowpart, SMALLC), 1.0f - SMALLC);
          float d = gam - g0l;
          nrm += d * d;
        }
      }
      // element y: row j = 2q+1
      {
        int i = tid + NT * (2 * q + 1);
        float si = sf2[q].y;
        float xj = x2[q].y;
        float pw = t2[q].y * inv_n;
        float rowpart = 0.0f;
        float* op = out + (size_t)(b * NN + i) * KK;
        #pragma unroll
        for (int c = 0; c < KK; ++c){
          float gam = pw * vt[c];
          pw *= xj;
          float z = fabsf(tkr[c] - si) / tauv;
          float raw1 = 1.0f / (1.0f + expf(z)) + SMALLC;
          float g0 = (raw1 / colr[c]) * inv_n;
          rowpart += g0;
          float d = gam - g0;
          nrm += d * d;
          op[c] = gam * (float)NN;
        }
        {
          float gam = pw * vt[KK];
          float g0l = fminf(fmaxf(inv_n - rowpart, SMALLC), 1.0f - SMALLC);
          float d = gam - g0l;
          nrm += d * d;
        }
      }
    }
  }
  #pragma unroll
  for (int off = 32; off; off >>= 1) nrm += __shfl_xor(nrm, off);
  if (lane == 0) rv[wv] = nrm;
  __syncthreads();
  if (tid == 0){
    float t = 0.0f;
    for (int q = 0; q < NW; ++q) t += rv[q];
    atomicAdd(reinterpret_cast<float*>(ws) + 2, t);
    __threadfence();
    unsigned prev = atomicAdd(&ws[4], 1u);
    if (prev == (unsigned)(BSZ - 1)){
      float n2 = __hip_atomic_load(reinterpret_cast<float*>(ws) + 2,
                                   __ATOMIC_RELAXED, __HIP_MEMORY_SCOPE_AGENT);
      out[OUT_A_ELEMS] = sqrtf(n2);
    }
  }
}

extern "C" void kernel_launch(void* const* d_in, const int* in_sizes, int n_in,
                              void* d_out, int out_size, void* d_ws, size_t ws_size,
                              hipStream_t stream){
  const float* scores = (const float*)d_in[0];
  const float* tau    = (const float*)d_in[1];
  const float* w1     = (const float*)d_in[2];  // (4111, 5) row-major
  const float* w2     = (const float*)d_in[3];  // (5, 65536) row-major
  float* out = (float*)d_out;
  unsigned* ws = (unsigned*)d_ws;

  // [0]=max_enc 0, [1]=neg 0, [2]=norm 0.f, [3]=arrive 0, [4]=done 0, [5]=min_enc FF
  hipMemsetAsync(ws, 0x00, 20, stream);
  hipMemsetAsync((char*)ws + 20, 0xFF, 4, stream);

  k_main<<<BSZ, NT, 0, stream>>>(scores, tau, w1, w2, out, ws);
}